// Round 20
// baseline (59.430 us; speedup 1.0000x reference)
//
#include <hip/hip_runtime.h>
#include <hip/hip_bf16.h>
#include <math.h>

#define NB 2
#define NT 256
#define NN 512
#define NH 64
#define NS 8
#define NC 8

// workspace layout (float offsets)
#define OFF_H      0          // 65536  h f32
#define OFF_PVEC   65536      // 65536  pre_i + be1
#define OFF_HF16   131072     // 32768 dwords: h packed f16
#define OFF_INVN   163840     // 1024
#define OFF_WA16   164864     // 2048 floats = 4096 f16 (Wa frags)
#define OFF_WJF    166912     // 4096 floats (Wj, frag order)
#define OFF_WPF    171008     // 4096 floats (Wp, frag order)
#define OFF_UNSYM  175104     // 524288
#define OFF_UNSYMT (175104 + 524288)   // 524288 (transposed copy)

typedef __attribute__((ext_vector_type(8))) _Float16 h8;
typedef __attribute__((ext_vector_type(2))) __fp16 fp16x2;
typedef __attribute__((ext_vector_type(4))) float f32x4;
typedef __attribute__((ext_vector_type(4))) unsigned u4;
typedef __attribute__((ext_vector_type(2))) unsigned u2;

__device__ __forceinline__ float softplusf(float x){
  if (x > 20.f) return x;
  return log1pf(expf(x));
}

__device__ __forceinline__ unsigned pkh(float a, float b){
  fp16x2 h = __builtin_amdgcn_cvt_pkrtz(a, b);
  return __builtin_bit_cast(unsigned, h);
}

// f32 += dot of packed f16 pairs
__device__ __forceinline__ float fdot2u(unsigned a, unsigned b, float c){
#if __has_builtin(__builtin_amdgcn_fdot2)
  return __builtin_amdgcn_fdot2(__builtin_bit_cast(fp16x2, a),
                                __builtin_bit_cast(fp16x2, b), c, false);
#else
  fp16x2 av = __builtin_bit_cast(fp16x2, a);
  fp16x2 bv = __builtin_bit_cast(fp16x2, b);
  return fmaf((float)av.x, (float)bv.x, fmaf((float)av.y, (float)bv.y, c));
#endif
}
__device__ __forceinline__ float dot8(u4 a, u4 b, float acc){
  #pragma unroll
  for (int d = 0; d < 4; ++d) acc = fdot2u(a[d], b[d], acc);
  return acc;
}

template<int CTRL>
__device__ __forceinline__ float dpp_addf(float x){
  int xi = __builtin_bit_cast(int, x);
  int yi = __builtin_amdgcn_update_dpp(0, xi, CTRL, 0xF, 0xF, true);
  return x + __builtin_bit_cast(float, yi);
}
__device__ __forceinline__ float row16_sum(float x){
  x = dpp_addf<0xB1>(x);    // lane^1
  x = dpp_addf<0x4E>(x);    // lane^2
  x = dpp_addf<0x141>(x);   // lane^7
  x = dpp_addf<0x140>(x);   // lane^15
  return x;
}

// ---------------- Kernel FRONT: stats + node MLP + weight prep ----------------
__global__ __launch_bounds__(256) void k_front(
    const float* __restrict__ x, const float* __restrict__ mask,
    const float* __restrict__ sctx,
    const float* __restrict__ W1, const float* __restrict__ b1,
    const float* __restrict__ W2, const float* __restrict__ b2,
    const float* __restrict__ We1, const float* __restrict__ be1,
    float* __restrict__ hg, float* __restrict__ pvec,
    unsigned* __restrict__ hf16, float* __restrict__ invn,
    short* __restrict__ wa16, float* __restrict__ wjf,
    float* __restrict__ wpf){
  int blk = blockIdx.x;
  int tid = threadIdx.x;

  if (blk >= 256){
    int pidx = (blk - 256)*256 + tid;        // 0..12287
    int e    = pidx & 7;
    int lane = (pidx >> 3) & 63;
    int frag = (pidx >> 9) & 7;              // ks*4+nt
    int nt = frag & 3, ks = frag >> 2;
    int kg = lane >> 4, q = lane & 15;
    int kk = ks*32 + kg*8 + e;
    int c  = nt*16 + q;
    if (pidx < 4096){
      _Float16 v = (_Float16)We1[(128 + kk)*NH + c];       // Wa rows 128..191
      wa16[pidx] = __builtin_bit_cast(short, v);
    } else if (pidx < 8192){
      wjf[pidx - 4096] = We1[(64 + kk)*NH + c];            // Wj rows 64..127
    } else {
      wpf[pidx - 8192] = We1[(192 + kk)*NH + c];           // Wp rows 192..255
    }
    return;
  }

  int b  = blk >> 7;
  int n0 = (blk & 127) * 4;

  // ---- stats: 4 nl x 64 ts ----
  int nl = tid & 3;
  int ts = tid >> 2;
  int n  = n0 + nl;

  float cnt = 0.f, sx = 0.f, sxx = 0.f;
  int lastt = 0;
  for (int t = ts*4; t < ts*4 + 4; ++t){
    int idx = (b*NT + t)*NN + n;
    float xv = x[idx];
    float mv = mask[idx];
    bool obs = (mv < 0.5f);
    if (obs){ cnt += 1.f; sx += xv; sxx += xv*xv; lastt = t; }
  }
  #pragma unroll
  for (int m = 4; m < 64; m <<= 1){
    cnt   += __shfl_xor(cnt,  m);
    sx    += __shfl_xor(sx,   m);
    sxx   += __shfl_xor(sxx,  m);
    lastt  = max(lastt, __shfl_xor(lastt, m));
  }
  int w = tid >> 6;
  __shared__ float r_cnt[4][4], r_sx[4][4], r_sxx[4][4];
  __shared__ int   r_lt[4][4];
  __shared__ float s_dyn[4][4];
  if ((tid & 63) < 4){
    r_cnt[w][nl] = cnt; r_sx[w][nl] = sx; r_sxx[w][nl] = sxx; r_lt[w][nl] = lastt;
  }
  __syncthreads();
  if (tid < 4){
    float c = 0.f, s1 = 0.f, s2 = 0.f; int lt = 0;
    #pragma unroll
    for (int ww = 0; ww < 4; ++ww){
      c  += r_cnt[ww][tid]; s1 += r_sx[ww][tid]; s2 += r_sxx[ww][tid];
      lt  = max(lt, r_lt[ww][tid]);
    }
    float cc   = fmaxf(c, 1.f);
    float mean = s1 / cc;
    float var  = s2 / cc - mean*mean;
    float stdv = sqrtf(fmaxf(var, 0.f) + 1e-6f);
    float last = x[(b*NT + lt)*NN + n0 + tid];
    float mr   = 1.f - c * (1.f/(float)NT);
    s_dyn[tid][0] = mean; s_dyn[tid][1] = stdv; s_dyn[tid][2] = last; s_dyn[tid][3] = mr;
  }
  __syncthreads();

  // ---- node MLP: wave w = node n0+w, lane c = channel ----
  int c = tid & 63;
  int gn = n0 + w;
  int bn = b*NN + gn;
  __shared__ float s_f[4][12];
  __shared__ float s_h1[4][64];
  __shared__ float s_h2[4][64];

  if (c < 4)       s_f[w][c] = s_dyn[w][c];
  else if (c < 12) s_f[w][c] = sctx[gn*NS + (c-4)];
  __syncthreads();

  float a = b1[c];
  #pragma unroll
  for (int k = 0; k < 12; ++k) a = fmaf(s_f[w][k], W1[k*NH + c], a);
  s_h1[w][c] = fmaxf(a, 0.f);
  __syncthreads();

  // 4-way split accumulators (shorten dependent fma chain 64 -> 16)
  float t0 = 0.f, t1 = 0.f, t2 = 0.f, t3 = 0.f;
  #pragma unroll 4
  for (int k = 0; k < 64; k += 4){
    t0 = fmaf(s_h1[w][k],     W2[(k)*NH + c],     t0);
    t1 = fmaf(s_h1[w][k + 1], W2[(k + 1)*NH + c], t1);
    t2 = fmaf(s_h1[w][k + 2], W2[(k + 2)*NH + c], t2);
    t3 = fmaf(s_h1[w][k + 3], W2[(k + 3)*NH + c], t3);
  }
  float a2 = b2[c] + ((t0 + t1) + (t2 + t3));
  a2 = fmaxf(a2, 0.f);

  float sq = a2*a2;
  #pragma unroll
  for (int m = 1; m < 64; m <<= 1) sq += __shfl_xor(sq, m);
  float inv = 1.f / fmaxf(sqrtf(sq), 1e-12f);

  s_h2[w][c] = a2;
  __syncthreads();

  float p0 = 0.f, p1 = 0.f, p2 = 0.f, p3 = 0.f;
  #pragma unroll 4
  for (int k = 0; k < 64; k += 4){
    p0 = fmaf(s_h2[w][k],     We1[(k)*NH + c],     p0);
    p1 = fmaf(s_h2[w][k + 1], We1[(k + 1)*NH + c], p1);
    p2 = fmaf(s_h2[w][k + 2], We1[(k + 2)*NH + c], p2);
    p3 = fmaf(s_h2[w][k + 3], We1[(k + 3)*NH + c], p3);
  }
  float pi = be1[c] + ((p0 + p1) + (p2 + p3));   // Wi rows 0..63

  hg  [bn*64 + c] = a2;
  pvec[bn*64 + c] = pi;
  if (c < 32){
    float e0 = s_h2[w][2*c], e1 = s_h2[w][2*c + 1];
    hf16[bn*32 + c] = pkh(e0, e1);
  }
  if (c == 0) invn[bn] = inv;
}

// ---------------- Kernel LOGITS: 4 i-rows/block, 1024 thr, fused softmax -----
// grid NB*NN/4 = 256 (1 block/CU, tail-free). 16 waves; wave w: tiles w, w+16
// (2 serial iters). Rows processed in 2 register passes (2 rows each).
__global__ __launch_bounds__(1024, 4) void k_logits(
    const float* __restrict__ hg, const float* __restrict__ pvec,
    const unsigned* __restrict__ hf16, const float* __restrict__ invn,
    const short* __restrict__ wa16, const float* __restrict__ wjf,
    const float* __restrict__ wpf, const float* __restrict__ coords,
    const float* __restrict__ We2, const float* __restrict__ be2,
    const float* __restrict__ s_sl, const float* __restrict__ s_ps,
    const float* __restrict__ s_ss, const float* __restrict__ s_tp,
    float* __restrict__ unsym, float* __restrict__ unsymT){
  int blk = blockIdx.x;
  int b  = blk >> 7;
  int ip = (blk & 127) * 4;          // rows ip .. ip+3
  int tid  = threadIdx.x;
  int w    = tid >> 6;               // 0..15
  int lane = tid & 63;
  int q    = lane & 15;
  int kg   = lane >> 4;
  int half = tid >> 9;               // 0..1 (row-pair selector)
  int jj   = tid & 511;

  __shared__ __align__(16) float s_hi[4][64];
  __shared__ __align__(16) float s_pri[4][NN];
  __shared__ __align__(16) float s_invn[NN];
  __shared__ __align__(16) float lrow[4][NN];
  __shared__ __align__(16) unsigned lds_wa[2048];
  __shared__ __align__(16) unsigned lds_cw[4][2048];
  __shared__ __align__(16) unsigned s_hj[16][16*34 + 2];
  __shared__ float red[64];

  float spsl = softplusf(s_sl[0]);
  float spps = softplusf(s_ps[0]);
  float spss = softplusf(s_ss[0]);
  float invt = 1.f / (softplusf(s_tp[0]) + 1e-4f);
  float be2v = be2[0];

  if (tid < 256)
    s_hi[tid >> 6][tid & 63] = hg[(b*NN + ip + (tid >> 6))*64 + (tid & 63)];
  // prior + invn: each thread handles 1 j for its row-pair
  {
    int j = jj;
    float4 cj0 = *(const float4*)(coords + j*NC);
    float4 cj1 = *(const float4*)(coords + j*NC + 4);
    #pragma unroll
    for (int r = 0; r < 2; ++r){
      int row = half*2 + r;
      int i = ip + row;
      float4 ci0 = *(const float4*)(coords + i*NC);
      float4 ci1 = *(const float4*)(coords + i*NC + 4);
      float dd = 0.f;
      dd = fmaf(ci0.x-cj0.x, ci0.x-cj0.x, dd);
      dd = fmaf(ci0.y-cj0.y, ci0.y-cj0.y, dd);
      dd = fmaf(ci0.z-cj0.z, ci0.z-cj0.z, dd);
      dd = fmaf(ci0.w-cj0.w, ci0.w-cj0.w, dd);
      dd = fmaf(ci1.x-cj1.x, ci1.x-cj1.x, dd);
      dd = fmaf(ci1.y-cj1.y, ci1.y-cj1.y, dd);
      dd = fmaf(ci1.z-cj1.z, ci1.z-cj1.z, dd);
      dd = fmaf(ci1.w-cj1.w, ci1.w-cj1.w, dd);
      float dist = sqrtf(fmaxf(dd, 1e-12f));
      s_pri[row][j] = (j == i) ? be2v : fmaf(spps, 1.f/(1.f + dist), be2v);
    }
    if (half == 0) s_invn[j] = invn[b*NN + j];
  }
  __syncthreads();   // s_hi ready

  // B-frags: wa copy (half 0) + cw = f16(Wj + diag(hi)*Wp) per row-pair
  {
    int frag = (tid >> 6) & 7;
    int l2   = tid & 63;
    if (half == 0)
      *(u4*)&lds_wa[(frag*64 + l2)*4] = ((const u4*)wa16)[frag*64 + l2];

    int ch0 = (frag >> 2)*32 + (l2 >> 4)*8;
    const float* wj = wjf + (frag*64 + l2)*8;
    const float* wp = wpf + (frag*64 + l2)*8;
    #pragma unroll
    for (int r = 0; r < 2; ++r){
      int row = half*2 + r;
      u4 u;
      #pragma unroll
      for (int d = 0; d < 4; ++d){
        float v0 = fmaf(s_hi[row][ch0 + 2*d],     wp[2*d],     wj[2*d]);
        float v1 = fmaf(s_hi[row][ch0 + 2*d + 1], wp[2*d + 1], wj[2*d + 1]);
        u[d] = pkh(v0, v1);
      }
      *(u4*)&lds_cw[row][(frag*64 + l2)*4] = u;
    }
  }

  const u4* hfv = (const u4*)hf16;
  float pv4[4][4], we2q[4];
  #pragma unroll
  for (int nt = 0; nt < 4; ++nt){
    #pragma unroll
    for (int row = 0; row < 4; ++row)
      pv4[row][nt] = pvec[(b*NN + ip + row)*64 + nt*16 + q];
    we2q[nt] = We2[nt*16 + q];
  }
  float invni[4];
  #pragma unroll
  for (int row = 0; row < 4; ++row) invni[row] = invn[b*NN + ip + row];
  int srcl = (lane & 48) | (((lane >> 4) & 3) << 2) | (lane & 3);
  int r8 = lane >> 3, c8 = lane & 7;
  __syncthreads();   // lds_wa / lds_cw ready

  const u4 absm = (u4){0x7fff7fffu, 0x7fff7fffu, 0x7fff7fffu, 0x7fff7fffu};
  unsigned* slice = &s_hj[w][0];

  // prefetch tile s=0
  u4 g0, g1;
  {
    int jbase = w * 16;
    g0 = *(const u4*)((const unsigned*)hf16 + (size_t)(b*NN + jbase + r8)*32 + c8*4);
    g1 = *(const u4*)((const unsigned*)hf16 + (size_t)(b*NN + jbase + 8 + r8)*32 + c8*4);
  }

  #pragma unroll
  for (int s = 0; s < 2; ++s){
    int jbase = (w + s*16) * 16;

    // write staged regs to this wave's slice (wave-private, in-order safe)
    {
      unsigned* p0 = slice + r8*34 + c8*4;
      unsigned* p1 = slice + (8 + r8)*34 + c8*4;
      u2 t;
      t.x = g0.x; t.y = g0.y; *(u2*)p0 = t;
      t.x = g0.z; t.y = g0.w; *(u2*)(p0 + 2) = t;
      t.x = g1.x; t.y = g1.y; *(u2*)p1 = t;
      t.x = g1.z; t.y = g1.w; *(u2*)(p1 + 2) = t;
    }
    if (s == 0){
      int jn = (w + 16) * 16;
      g0 = *(const u4*)((const unsigned*)hf16 + (size_t)(b*NN + jn + r8)*32 + c8*4);
      g1 = *(const u4*)((const unsigned*)hf16 + (size_t)(b*NN + jn + 8 + r8)*32 + c8*4);
    }

    // this lane's hj fragment
    u4 hj0, hj1;
    {
      unsigned* rp = slice + q*34 + kg*4;
      u2 a0 = *(u2*)rp;
      u2 a1 = *(u2*)(rp + 2);
      u2 b0 = *(u2*)(rp + 16);
      u2 b1 = *(u2*)(rp + 18);
      hj0.x = a0.x; hj0.y = a0.y; hj0.z = a1.x; hj0.w = a1.y;
      hj1.x = b0.x; hj1.y = b0.y; hj1.z = b1.x; hj1.w = b1.y;
    }
    h8 hjv0 = __builtin_bit_cast(h8, hj0);
    h8 hjv1 = __builtin_bit_cast(h8, hj1);

    // 2 register passes x 2 rows
    #pragma unroll
    for (int p = 0; p < 2; ++p){
      u4 hiA[2][2];
      #pragma unroll
      for (int r = 0; r < 2; ++r){
        hiA[r][0] = hfv[(b*NN + ip + 2*p + r)*8 + kg];
        hiA[r][1] = hfv[(b*NN + ip + 2*p + r)*8 + kg + 4];
      }
      float dotp[2];
      #pragma unroll
      for (int r = 0; r < 2; ++r){
        float d0 = dot8(hiA[r][0], hj0, 0.f);
        dotp[r]  = dot8(hiA[r][1], hj1, d0);
      }

      f32x4 acc[2][4];
      #pragma unroll
      for (int r = 0; r < 2; ++r)
        #pragma unroll
        for (int nt = 0; nt < 4; ++nt){
          float pv = pv4[2*p + r][nt];
          acc[r][nt] = (f32x4){pv, pv, pv, pv};
        }

      #pragma unroll
      for (int nt = 0; nt < 4; ++nt){
        h8 wA0 = __builtin_bit_cast(h8, *(const u4*)&lds_wa[((0*4 + nt)*64 + lane)*4]);
        h8 wA1 = __builtin_bit_cast(h8, *(const u4*)&lds_wa[((1*4 + nt)*64 + lane)*4]);
        #pragma unroll
        for (int r = 0; r < 2; ++r){
          int row = 2*p + r;
          h8 dh0 = __builtin_bit_cast(h8, hiA[r][0]) - hjv0;
          h8 dh1 = __builtin_bit_cast(h8, hiA[r][1]) - hjv1;
          h8 af0 = __builtin_bit_cast(h8, __builtin_bit_cast(u4, dh0) & absm);
          h8 af1 = __builtin_bit_cast(h8, __builtin_bit_cast(u4, dh1) & absm);
          h8 wC0 = __builtin_bit_cast(h8, *(const u4*)&lds_cw[row][((0*4 + nt)*64 + lane)*4]);
          h8 wC1 = __builtin_bit_cast(h8, *(const u4*)&lds_cw[row][((1*4 + nt)*64 + lane)*4]);
          acc[r][nt] = __builtin_amdgcn_mfma_f32_16x16x32_f16(af0, wA0, acc[r][nt], 0, 0, 0);
          acc[r][nt] = __builtin_amdgcn_mfma_f32_16x16x32_f16(af1, wA1, acc[r][nt], 0, 0, 0);
          acc[r][nt] = __builtin_amdgcn_mfma_f32_16x16x32_f16(hjv0, wC0, acc[r][nt], 0, 0, 0);
          acc[r][nt] = __builtin_amdgcn_mfma_f32_16x16x32_f16(hjv1, wC1, acc[r][nt], 0, 0, 0);
        }
      }

      #pragma unroll
      for (int r = 0; r < 2; ++r){
        int row = 2*p + r;
        float part[4] = {0.f, 0.f, 0.f, 0.f};
        #pragma unroll
        for (int nt = 0; nt < 4; ++nt)
          #pragma unroll
          for (int rr = 0; rr < 4; ++rr)
            part[rr] = fmaf(fmaxf(acc[r][nt][rr], 0.f), we2q[nt], part[rr]);
        #pragma unroll
        for (int rr = 0; rr < 4; ++rr) part[rr] = row16_sum(part[rr]);

        float dp = dotp[r];
        dp += __shfl_xor(dp, 16);
        dp += __shfl_xor(dp, 32);
        float dj = __shfl(dp, srcl);

        if (q < 4){
          int j2 = jbase + kg*4 + q;
          float ps2 = part[0];
          ps2 = (q == 1) ? part[1] : ps2;
          ps2 = (q == 2) ? part[2] : ps2;
          ps2 = (q == 3) ? part[3] : ps2;
          float cosv = dj * invni[row] * s_invn[j2];
          lrow[row][j2] = ps2 + s_pri[row][j2] + spss * cosv;
        }
      }
    }
  }
  __syncthreads();

  // fused 4-row softmax: row-pair (2*half, 2*half+1), 1 j per thread
  {
    int p = half;
    int j = jj;
    int ra = 2*p, rb = 2*p + 1;
    float va = (j == ip + ra) ? spsl : lrow[ra][j];
    float vb = (j == ip + rb) ? spsl : lrow[rb][j];

    float ma = va, mb = vb;
    #pragma unroll
    for (int msk = 1; msk < 64; msk <<= 1){
      ma = fmaxf(ma, __shfl_xor(ma, msk));
      mb = fmaxf(mb, __shfl_xor(mb, msk));
    }
    if (lane == 0){ red[w] = ma; red[16 + w] = mb; }
    __syncthreads();
    ma = red[p*8]; mb = red[16 + p*8];
    #pragma unroll
    for (int ww = 1; ww < 8; ++ww){
      ma = fmaxf(ma, red[p*8 + ww]);
      mb = fmaxf(mb, red[16 + p*8 + ww]);
    }

    float ea = expf((va - ma) * invt);
    float eb = expf((vb - mb) * invt);
    float sa = ea, sb = eb;
    #pragma unroll
    for (int msk = 1; msk < 64; msk <<= 1){
      sa += __shfl_xor(sa, msk);
      sb += __shfl_xor(sb, msk);
    }
    if (lane == 0){ red[32 + w] = sa; red[48 + w] = sb; }
    __syncthreads();
    sa = red[32 + p*8]; sb = red[48 + p*8];
    #pragma unroll
    for (int ww = 1; ww < 8; ++ww){
      sa += red[32 + p*8 + ww];
      sb += red[48 + p*8 + ww];
    }

    float oa = ea / sa;
    float ob = eb / sb;
    unsym[(size_t)(b*NN + ip + ra)*NN + j] = oa;
    unsym[(size_t)(b*NN + ip + rb)*NN + j] = ob;
    *(float2*)(unsymT + (size_t)(b*NN + j)*NN + ip + 2*p) = (float2){oa, ob};
  }
}

// ---------------- Kernel D: symmetrize + renormalize (fully coalesced) -------
__global__ __launch_bounds__(512) void k_sym(
    const float* __restrict__ u, const float* __restrict__ ut,
    float* __restrict__ out){
  int blk = blockIdx.x;
  int b  = blk >> 8;
  int ip = (blk & 255) * 2;
  int tid  = threadIdx.x;
  int lane = tid & 63, w = tid >> 6;

  const float* ra  = u  + (size_t)(b*NN + ip) * NN;
  const float* rat = ut + (size_t)(b*NN + ip) * NN;
  const float* rb  = u  + (size_t)(b*NN + ip + 1) * NN;
  const float* rbt = ut + (size_t)(b*NN + ip + 1) * NN;
  float va = 0.5f*(ra[tid] + rat[tid]);
  float vb = 0.5f*(rb[tid] + rbt[tid]);

  float sa = va, sb = vb;
  #pragma unroll
  for (int msk = 1; msk < 64; msk <<= 1){
    sa += __shfl_xor(sa, msk);
    sb += __shfl_xor(sb, msk);
  }
  __shared__ float red[16];
  if (lane == 0){ red[w] = sa; red[8 + w] = sb; }
  __syncthreads();
  sa = red[0]; sb = red[8];
  #pragma unroll
  for (int ww = 1; ww < 8; ++ww){
    sa += red[ww];
    sb += red[8 + ww];
  }
  float ia = 1.f / fmaxf(sa, 1e-6f);
  float ib = 1.f / fmaxf(sb, 1e-6f);
  out[(size_t)(b*NN + ip)*NN + tid]     = va * ia;
  out[(size_t)(b*NN + ip + 1)*NN + tid] = vb * ib;
}

extern "C" void kernel_launch(void* const* d_in, const int* in_sizes, int n_in,
                              void* d_out, int out_size, void* d_ws, size_t ws_size,
                              hipStream_t stream){
  const float* x      = (const float*)d_in[0];
  const float* mask   = (const float*)d_in[1];
  const float* sctx   = (const float*)d_in[2];
  const float* coords = (const float*)d_in[3];
  const float* W1     = (const float*)d_in[4];
  const float* b1     = (const float*)d_in[5];
  const float* W2     = (const float*)d_in[6];
  const float* b2     = (const float*)d_in[7];
  const float* We1    = (const float*)d_in[8];
  const float* be1    = (const float*)d_in[9];
  const float* We2    = (const float*)d_in[10];
  const float* be2    = (const float*)d_in[11];
  const float* sl     = (const float*)d_in[12];
  const float* ps     = (const float*)d_in[13];
  const float* ss     = (const float*)d_in[14];
  const float* tp     = (const float*)d_in[15];

  float*    ws     = (float*)d_ws;
  float*    hgp    = ws + OFF_H;
  float*    pvecp  = ws + OFF_PVEC;
  unsigned* hf16p  = (unsigned*)(ws + OFF_HF16);
  float*    invnp  = ws + OFF_INVN;
  short*    wa16p  = (short*)(ws + OFF_WA16);
  float*    wjfp   = ws + OFF_WJF;
  float*    wpfp   = ws + OFF_WPF;
  float*    unsym  = ws + OFF_UNSYM;
  float*    unsymT = ws + OFF_UNSYMT;
  float*    out    = (float*)d_out;

  k_front <<<304, 256, 0, stream>>>(x, mask, sctx, W1, b1, W2, b2, We1, be1,
                                    hgp, pvecp, hf16p, invnp, wa16p, wjfp, wpfp);
  k_logits<<<NB*NN/4, 1024, 0, stream>>>(hgp, pvecp, hf16p, invnp, wa16p, wjfp,
                                         wpfp, coords, We2, be2, sl, ps, ss, tp,
                                         unsym, unsymT);
  k_sym   <<<NB*NN/2, 512, 0, stream>>>(unsym, unsymT, out);
}

// Round 21
// 40.115 us; speedup vs baseline: 1.4815x; 1.4815x over previous
//
#include <hip/hip_runtime.h>
#include <hip/hip_bf16.h>
#include <math.h>

#define NB 2
#define NT 256
#define NN 512
#define NH 64
#define NS 8
#define NC 8

// workspace layout (float offsets)
#define OFF_H      0          // 65536  h f32
#define OFF_PVEC   65536      // 65536  pre_i + be1
#define OFF_HF16   131072     // 32768 dwords: h packed f16
#define OFF_INVN   163840     // 1024
#define OFF_WA16   164864     // 2048 floats = 4096 f16 (Wa frags)
#define OFF_WJF    166912     // 4096 floats (Wj, frag order)
#define OFF_WPF    171008     // 4096 floats (Wp, frag order)
#define OFF_UNSYM  175104     // 524288
#define OFF_UNSYMT (175104 + 524288)   // 524288 (transposed copy)

typedef __attribute__((ext_vector_type(8))) _Float16 h8;
typedef __attribute__((ext_vector_type(2))) __fp16 fp16x2;
typedef __attribute__((ext_vector_type(4))) float f32x4;
typedef __attribute__((ext_vector_type(4))) unsigned u4;
typedef __attribute__((ext_vector_type(2))) unsigned u2;

__device__ __forceinline__ float softplusf(float x){
  if (x > 20.f) return x;
  return log1pf(expf(x));
}

__device__ __forceinline__ unsigned pkh(float a, float b){
  fp16x2 h = __builtin_amdgcn_cvt_pkrtz(a, b);
  return __builtin_bit_cast(unsigned, h);
}

// f32 += dot of packed f16 pairs
__device__ __forceinline__ float fdot2u(unsigned a, unsigned b, float c){
#if __has_builtin(__builtin_amdgcn_fdot2)
  return __builtin_amdgcn_fdot2(__builtin_bit_cast(fp16x2, a),
                                __builtin_bit_cast(fp16x2, b), c, false);
#else
  fp16x2 av = __builtin_bit_cast(fp16x2, a);
  fp16x2 bv = __builtin_bit_cast(fp16x2, b);
  return fmaf((float)av.x, (float)bv.x, fmaf((float)av.y, (float)bv.y, c));
#endif
}
__device__ __forceinline__ float dot8(u4 a, u4 b, float acc){
  #pragma unroll
  for (int d = 0; d < 4; ++d) acc = fdot2u(a[d], b[d], acc);
  return acc;
}

template<int CTRL>
__device__ __forceinline__ float dpp_addf(float x){
  int xi = __builtin_bit_cast(int, x);
  int yi = __builtin_amdgcn_update_dpp(0, xi, CTRL, 0xF, 0xF, true);
  return x + __builtin_bit_cast(float, yi);
}
__device__ __forceinline__ float row16_sum(float x){
  x = dpp_addf<0xB1>(x);    // lane^1
  x = dpp_addf<0x4E>(x);    // lane^2
  x = dpp_addf<0x141>(x);   // lane^7
  x = dpp_addf<0x140>(x);   // lane^15
  return x;
}

// ---------------- Kernel FRONT: stats + node MLP + weight prep ----------------
__global__ __launch_bounds__(256) void k_front(
    const float* __restrict__ x, const float* __restrict__ mask,
    const float* __restrict__ sctx,
    const float* __restrict__ W1, const float* __restrict__ b1,
    const float* __restrict__ W2, const float* __restrict__ b2,
    const float* __restrict__ We1, const float* __restrict__ be1,
    float* __restrict__ hg, float* __restrict__ pvec,
    unsigned* __restrict__ hf16, float* __restrict__ invn,
    short* __restrict__ wa16, float* __restrict__ wjf,
    float* __restrict__ wpf){
  int blk = blockIdx.x;
  int tid = threadIdx.x;

  if (blk >= 256){
    int pidx = (blk - 256)*256 + tid;        // 0..12287
    int e    = pidx & 7;
    int lane = (pidx >> 3) & 63;
    int frag = (pidx >> 9) & 7;              // ks*4+nt
    int nt = frag & 3, ks = frag >> 2;
    int kg = lane >> 4, q = lane & 15;
    int kk = ks*32 + kg*8 + e;
    int c  = nt*16 + q;
    if (pidx < 4096){
      _Float16 v = (_Float16)We1[(128 + kk)*NH + c];       // Wa rows 128..191
      wa16[pidx] = __builtin_bit_cast(short, v);
    } else if (pidx < 8192){
      wjf[pidx - 4096] = We1[(64 + kk)*NH + c];            // Wj rows 64..127
    } else {
      wpf[pidx - 8192] = We1[(192 + kk)*NH + c];           // Wp rows 192..255
    }
    return;
  }

  int b  = blk >> 7;
  int n0 = (blk & 127) * 4;

  // ---- stats: 4 nl x 64 ts ----
  int nl = tid & 3;
  int ts = tid >> 2;
  int n  = n0 + nl;

  float cnt = 0.f, sx = 0.f, sxx = 0.f;
  int lastt = 0;
  for (int t = ts*4; t < ts*4 + 4; ++t){
    int idx = (b*NT + t)*NN + n;
    float xv = x[idx];
    float mv = mask[idx];
    bool obs = (mv < 0.5f);
    if (obs){ cnt += 1.f; sx += xv; sxx += xv*xv; lastt = t; }
  }
  #pragma unroll
  for (int m = 4; m < 64; m <<= 1){
    cnt   += __shfl_xor(cnt,  m);
    sx    += __shfl_xor(sx,   m);
    sxx   += __shfl_xor(sxx,  m);
    lastt  = max(lastt, __shfl_xor(lastt, m));
  }
  int w = tid >> 6;
  __shared__ float r_cnt[4][4], r_sx[4][4], r_sxx[4][4];
  __shared__ int   r_lt[4][4];
  __shared__ float s_dyn[4][4];
  if ((tid & 63) < 4){
    r_cnt[w][nl] = cnt; r_sx[w][nl] = sx; r_sxx[w][nl] = sxx; r_lt[w][nl] = lastt;
  }
  __syncthreads();
  if (tid < 4){
    float c = 0.f, s1 = 0.f, s2 = 0.f; int lt = 0;
    #pragma unroll
    for (int ww = 0; ww < 4; ++ww){
      c  += r_cnt[ww][tid]; s1 += r_sx[ww][tid]; s2 += r_sxx[ww][tid];
      lt  = max(lt, r_lt[ww][tid]);
    }
    float cc   = fmaxf(c, 1.f);
    float mean = s1 / cc;
    float var  = s2 / cc - mean*mean;
    float stdv = sqrtf(fmaxf(var, 0.f) + 1e-6f);
    float last = x[(b*NT + lt)*NN + n0 + tid];
    float mr   = 1.f - c * (1.f/(float)NT);
    s_dyn[tid][0] = mean; s_dyn[tid][1] = stdv; s_dyn[tid][2] = last; s_dyn[tid][3] = mr;
  }
  __syncthreads();

  // ---- node MLP: wave w = node n0+w, lane c = channel ----
  int c = tid & 63;
  int gn = n0 + w;
  int bn = b*NN + gn;
  __shared__ float s_f[4][12];
  __shared__ float s_h1[4][64];
  __shared__ float s_h2[4][64];

  if (c < 4)       s_f[w][c] = s_dyn[w][c];
  else if (c < 12) s_f[w][c] = sctx[gn*NS + (c-4)];
  __syncthreads();

  float a = b1[c];
  #pragma unroll
  for (int k = 0; k < 12; ++k) a = fmaf(s_f[w][k], W1[k*NH + c], a);
  s_h1[w][c] = fmaxf(a, 0.f);
  __syncthreads();

  // 4-way split accumulators (shorten dependent fma chain 64 -> 16)
  float t0 = 0.f, t1 = 0.f, t2 = 0.f, t3 = 0.f;
  #pragma unroll 4
  for (int k = 0; k < 64; k += 4){
    t0 = fmaf(s_h1[w][k],     W2[(k)*NH + c],     t0);
    t1 = fmaf(s_h1[w][k + 1], W2[(k + 1)*NH + c], t1);
    t2 = fmaf(s_h1[w][k + 2], W2[(k + 2)*NH + c], t2);
    t3 = fmaf(s_h1[w][k + 3], W2[(k + 3)*NH + c], t3);
  }
  float a2 = b2[c] + ((t0 + t1) + (t2 + t3));
  a2 = fmaxf(a2, 0.f);

  float sq = a2*a2;
  #pragma unroll
  for (int m = 1; m < 64; m <<= 1) sq += __shfl_xor(sq, m);
  float inv = 1.f / fmaxf(sqrtf(sq), 1e-12f);

  s_h2[w][c] = a2;
  __syncthreads();

  float p0 = 0.f, p1 = 0.f, p2 = 0.f, p3 = 0.f;
  #pragma unroll 4
  for (int k = 0; k < 64; k += 4){
    p0 = fmaf(s_h2[w][k],     We1[(k)*NH + c],     p0);
    p1 = fmaf(s_h2[w][k + 1], We1[(k + 1)*NH + c], p1);
    p2 = fmaf(s_h2[w][k + 2], We1[(k + 2)*NH + c], p2);
    p3 = fmaf(s_h2[w][k + 3], We1[(k + 3)*NH + c], p3);
  }
  float pi = be1[c] + ((p0 + p1) + (p2 + p3));   // Wi rows 0..63

  hg  [bn*64 + c] = a2;
  pvec[bn*64 + c] = pi;
  if (c < 32){
    float e0 = s_h2[w][2*c], e1 = s_h2[w][2*c + 1];
    hf16[bn*32 + c] = pkh(e0, e1);
  }
  if (c == 0) invn[bn] = inv;
}

// ---------------- Kernel LOGITS: 2 i-rows/block + T14 prefetch + softmax -----
// Also emits the transposed adjacency copy (unsymT[j][i] = unsym[i][j]) so
// k_sym never does a strided column gather.
__global__ __launch_bounds__(512, 4) void k_logits(
    const float* __restrict__ hg, const float* __restrict__ pvec,
    const unsigned* __restrict__ hf16, const float* __restrict__ invn,
    const short* __restrict__ wa16, const float* __restrict__ wjf,
    const float* __restrict__ wpf, const float* __restrict__ coords,
    const float* __restrict__ We2, const float* __restrict__ be2,
    const float* __restrict__ s_sl, const float* __restrict__ s_ps,
    const float* __restrict__ s_ss, const float* __restrict__ s_tp,
    float* __restrict__ unsym, float* __restrict__ unsymT){
  int blk = blockIdx.x;
  int b  = blk >> 8;
  int ip = (blk & 255) * 2;          // rows ip, ip+1
  int tid  = threadIdx.x;
  int w    = tid >> 6;
  int lane = tid & 63;
  int q    = lane & 15;
  int kg   = lane >> 4;

  __shared__ __align__(16) float s_hi[2][64];
  __shared__ __align__(16) float s_pri[2][NN];     // be2 + spps*prior
  __shared__ __align__(16) float s_invn[NN];
  __shared__ __align__(16) float lrow[2][NN];
  __shared__ __align__(16) unsigned lds_wa[2048];  // 8 frags x 64 x 4dw
  __shared__ __align__(16) unsigned lds_cw[2][2048];
  __shared__ __align__(16) unsigned s_hj[8][2][16*34 + 2];  // dbuf per wave
  __shared__ float red[32];

  float spsl = softplusf(s_sl[0]);
  float spps = softplusf(s_ps[0]);
  float spss = softplusf(s_ss[0]);
  float invt = 1.f / (softplusf(s_tp[0]) + 1e-4f);
  float be2v = be2[0];

  if (tid < 128)
    s_hi[tid >> 6][tid & 63] = hg[(b*NN + ip + (tid >> 6))*64 + (tid & 63)];
  // prior + invn per j (512 threads, 1 j each, 2 rows)
  {
    int j = tid;
    float4 cj0 = *(const float4*)(coords + j*NC);
    float4 cj1 = *(const float4*)(coords + j*NC + 4);
    #pragma unroll
    for (int r = 0; r < 2; ++r){
      int i = ip + r;
      float4 ci0 = *(const float4*)(coords + i*NC);
      float4 ci1 = *(const float4*)(coords + i*NC + 4);
      float dd = 0.f;
      dd = fmaf(ci0.x-cj0.x, ci0.x-cj0.x, dd);
      dd = fmaf(ci0.y-cj0.y, ci0.y-cj0.y, dd);
      dd = fmaf(ci0.z-cj0.z, ci0.z-cj0.z, dd);
      dd = fmaf(ci0.w-cj0.w, ci0.w-cj0.w, dd);
      dd = fmaf(ci1.x-cj1.x, ci1.x-cj1.x, dd);
      dd = fmaf(ci1.y-cj1.y, ci1.y-cj1.y, dd);
      dd = fmaf(ci1.z-cj1.z, ci1.z-cj1.z, dd);
      dd = fmaf(ci1.w-cj1.w, ci1.w-cj1.w, dd);
      float dist = sqrtf(fmaxf(dd, 1e-12f));
      s_pri[r][j] = (j == i) ? be2v : fmaf(spps, 1.f/(1.f + dist), be2v);
    }
    s_invn[j] = invn[b*NN + j];
  }
  __syncthreads();   // s_hi ready

  // B-frags in LDS: wa copy + per-row cw = f16(Wj + diag(hi)*Wp)
  {
    int frag = tid >> 6;          // 0..7 = ks*4+nt
    int l2   = tid & 63;
    const u4* wsrc = (const u4*)wa16;
    *(u4*)&lds_wa[(frag*64 + l2)*4] = wsrc[frag*64 + l2];

    int ch0 = (frag >> 2)*32 + (l2 >> 4)*8;
    const float* wj = wjf + (frag*64 + l2)*8;
    const float* wp = wpf + (frag*64 + l2)*8;
    #pragma unroll
    for (int r = 0; r < 2; ++r){
      u4 u;
      #pragma unroll
      for (int d = 0; d < 4; ++d){
        float v0 = fmaf(s_hi[r][ch0 + 2*d],     wp[2*d],     wj[2*d]);
        float v1 = fmaf(s_hi[r][ch0 + 2*d + 1], wp[2*d + 1], wj[2*d + 1]);
        u[d] = pkh(v0, v1);
      }
      *(u4*)&lds_cw[r][(frag*64 + l2)*4] = u;
    }
  }

  // per-lane hi packed f16 for both rows
  const u4* hfv = (const u4*)hf16;
  u4 hiA[2][2];
  #pragma unroll
  for (int r = 0; r < 2; ++r){
    hiA[r][0] = hfv[(b*NN + ip + r)*8 + kg];
    hiA[r][1] = hfv[(b*NN + ip + r)*8 + kg + 4];
  }

  float pv4[2][4], we2q[4];
  #pragma unroll
  for (int nt = 0; nt < 4; ++nt){
    #pragma unroll
    for (int r = 0; r < 2; ++r)
      pv4[r][nt] = pvec[(b*NN + ip + r)*64 + nt*16 + q];
    we2q[nt] = We2[nt*16 + q];
  }
  float invni[2];
  invni[0] = invn[b*NN + ip];
  invni[1] = invn[b*NN + ip + 1];
  int srcl = (lane & 48) | (((lane >> 4) & 3) << 2) | (lane & 3);
  int r8 = lane >> 3, c8 = lane & 7;
  __syncthreads();   // lds_wa / lds_cw ready

  const u4 absm = (u4){0x7fff7fffu, 0x7fff7fffu, 0x7fff7fffu, 0x7fff7fffu};

  // prefetch tile s=0 into regs
  u4 g0, g1;
  {
    int jbase = w * 16;
    g0 = *(const u4*)((const unsigned*)hf16 + (size_t)(b*NN + jbase + r8)*32 + c8*4);
    g1 = *(const u4*)((const unsigned*)hf16 + (size_t)(b*NN + jbase + 8 + r8)*32 + c8*4);
  }

  #pragma unroll
  for (int s = 0; s < 4; ++s){
    int jbase = (w + s*8) * 16;
    unsigned* slice = &s_hj[w][s & 1][0];

    // write current tile's staged regs to this wave's LDS slice
    {
      unsigned* p0 = slice + r8*34 + c8*4;
      unsigned* p1 = slice + (8 + r8)*34 + c8*4;
      u2 t;
      t.x = g0.x; t.y = g0.y; *(u2*)p0 = t;
      t.x = g0.z; t.y = g0.w; *(u2*)(p0 + 2) = t;
      t.x = g1.x; t.y = g1.y; *(u2*)p1 = t;
      t.x = g1.z; t.y = g1.w; *(u2*)(p1 + 2) = t;
    }
    // issue next tile's global loads (overlap with this tile's compute)
    if (s < 3){
      int jn = (w + (s+1)*8) * 16;
      g0 = *(const u4*)((const unsigned*)hf16 + (size_t)(b*NN + jn + r8)*32 + c8*4);
      g1 = *(const u4*)((const unsigned*)hf16 + (size_t)(b*NN + jn + 8 + r8)*32 + c8*4);
    }

    // this lane's hj fragment (row q, k-slices kg)
    u4 hj0, hj1;
    {
      unsigned* rp = slice + q*34 + kg*4;
      u2 a0 = *(u2*)rp;
      u2 a1 = *(u2*)(rp + 2);
      u2 b0 = *(u2*)(rp + 16);
      u2 b1 = *(u2*)(rp + 18);
      hj0.x = a0.x; hj0.y = a0.y; hj0.z = a1.x; hj0.w = a1.y;
      hj1.x = b0.x; hj1.y = b0.y; hj1.z = b1.x; hj1.w = b1.y;
    }
    h8 hjv0 = __builtin_bit_cast(h8, hj0);
    h8 hjv1 = __builtin_bit_cast(h8, hj1);

    // inline per-lane f16 dot (for cos): 16 channels, both rows
    float dotp[2];
    #pragma unroll
    for (int r = 0; r < 2; ++r){
      float d0 = dot8(hiA[r][0], hj0, 0.f);
      dotp[r]  = dot8(hiA[r][1], hj1, d0);
    }

    f32x4 acc[2][4];
    #pragma unroll
    for (int r = 0; r < 2; ++r)
      #pragma unroll
      for (int nt = 0; nt < 4; ++nt)
        acc[r][nt] = (f32x4){pv4[r][nt], pv4[r][nt], pv4[r][nt], pv4[r][nt]};

    #pragma unroll
    for (int nt = 0; nt < 4; ++nt){
      h8 wA0 = __builtin_bit_cast(h8, *(const u4*)&lds_wa[((0*4 + nt)*64 + lane)*4]);
      h8 wA1 = __builtin_bit_cast(h8, *(const u4*)&lds_wa[((1*4 + nt)*64 + lane)*4]);
      #pragma unroll
      for (int r = 0; r < 2; ++r){
        h8 dh0 = __builtin_bit_cast(h8, hiA[r][0]) - hjv0;
        h8 dh1 = __builtin_bit_cast(h8, hiA[r][1]) - hjv1;
        h8 af0 = __builtin_bit_cast(h8, __builtin_bit_cast(u4, dh0) & absm);
        h8 af1 = __builtin_bit_cast(h8, __builtin_bit_cast(u4, dh1) & absm);
        h8 wC0 = __builtin_bit_cast(h8, *(const u4*)&lds_cw[r][((0*4 + nt)*64 + lane)*4]);
        h8 wC1 = __builtin_bit_cast(h8, *(const u4*)&lds_cw[r][((1*4 + nt)*64 + lane)*4]);
        acc[r][nt] = __builtin_amdgcn_mfma_f32_16x16x32_f16(af0, wA0, acc[r][nt], 0, 0, 0);
        acc[r][nt] = __builtin_amdgcn_mfma_f32_16x16x32_f16(af1, wA1, acc[r][nt], 0, 0, 0);
        acc[r][nt] = __builtin_amdgcn_mfma_f32_16x16x32_f16(hjv0, wC0, acc[r][nt], 0, 0, 0);
        acc[r][nt] = __builtin_amdgcn_mfma_f32_16x16x32_f16(hjv1, wC1, acc[r][nt], 0, 0, 0);
      }
    }

    // epilogue per row: relu + We2 dot, DPP reduce; add prior + cos
    #pragma unroll
    for (int r = 0; r < 2; ++r){
      float part[4] = {0.f, 0.f, 0.f, 0.f};
      #pragma unroll
      for (int nt = 0; nt < 4; ++nt)
        #pragma unroll
        for (int rr = 0; rr < 4; ++rr)
          part[rr] = fmaf(fmaxf(acc[r][nt][rr], 0.f), we2q[nt], part[rr]);
      #pragma unroll
      for (int rr = 0; rr < 4; ++rr) part[rr] = row16_sum(part[rr]);

      float dp = dotp[r];
      dp += __shfl_xor(dp, 16);
      dp += __shfl_xor(dp, 32);
      float dj = __shfl(dp, srcl);     // dot for j = jbase + kg*4 + (lane&3)

      if (q < 4){
        int j2 = jbase + kg*4 + q;
        float ps2 = part[0];
        ps2 = (q == 1) ? part[1] : ps2;
        ps2 = (q == 2) ? part[2] : ps2;
        ps2 = (q == 3) ? part[3] : ps2;
        float cosv = dj * invni[r] * s_invn[j2];
        lrow[r][j2] = ps2 + s_pri[r][j2] + spss * cosv;
      }
    }
  }
  __syncthreads();

  // fused dual-row softmax; diag override here
  float va = (tid == ip)     ? spsl : lrow[0][tid];
  float vb = (tid == ip + 1) ? spsl : lrow[1][tid];

  float ma = va, mb = vb;
  #pragma unroll
  for (int msk = 1; msk < 64; msk <<= 1){
    ma = fmaxf(ma, __shfl_xor(ma, msk));
    mb = fmaxf(mb, __shfl_xor(mb, msk));
  }
  if (lane == 0){ red[w] = ma; red[8 + w] = mb; }
  __syncthreads();
  ma = red[0]; mb = red[8];
  #pragma unroll
  for (int ww = 1; ww < 8; ++ww){
    ma = fmaxf(ma, red[ww]);
    mb = fmaxf(mb, red[8 + ww]);
  }

  float ea = expf((va - ma) * invt);
  float eb = expf((vb - mb) * invt);
  float sa = ea, sb = eb;
  #pragma unroll
  for (int msk = 1; msk < 64; msk <<= 1){
    sa += __shfl_xor(sa, msk);
    sb += __shfl_xor(sb, msk);
  }
  if (lane == 0){ red[16 + w] = sa; red[24 + w] = sb; }
  __syncthreads();
  sa = red[16]; sb = red[24];
  #pragma unroll
  for (int ww = 1; ww < 8; ++ww){
    sa += red[16 + ww];
    sb += red[8 + 16 + ww];
  }

  float oa = ea / sa;
  float ob = eb / sb;
  unsym[(size_t)(b*NN + ip)*NN + tid]     = oa;
  unsym[(size_t)(b*NN + ip + 1)*NN + tid] = ob;
  // transposed copy: unsymT[tid][ip], unsymT[tid][ip+1] (one float2 scatter)
  *(float2*)(unsymT + (size_t)(b*NN + tid)*NN + ip) = (float2){oa, ob};
}

// ---------------- Kernel D: symmetrize + renormalize (fully coalesced) -------
__global__ __launch_bounds__(512) void k_sym(
    const float* __restrict__ u, const float* __restrict__ ut,
    float* __restrict__ out){
  int blk = blockIdx.x;
  int b  = blk >> 8;
  int ip = (blk & 255) * 2;
  int tid  = threadIdx.x;
  int lane = tid & 63, w = tid >> 6;

  const float* ra  = u  + (size_t)(b*NN + ip) * NN;
  const float* rat = ut + (size_t)(b*NN + ip) * NN;
  const float* rb  = u  + (size_t)(b*NN + ip + 1) * NN;
  const float* rbt = ut + (size_t)(b*NN + ip + 1) * NN;
  float va = 0.5f*(ra[tid] + rat[tid]);
  float vb = 0.5f*(rb[tid] + rbt[tid]);

  float sa = va, sb = vb;
  #pragma unroll
  for (int msk = 1; msk < 64; msk <<= 1){
    sa += __shfl_xor(sa, msk);
    sb += __shfl_xor(sb, msk);
  }
  __shared__ float red[16];
  if (lane == 0){ red[w] = sa; red[8 + w] = sb; }
  __syncthreads();
  sa = red[0]; sb = red[8];
  #pragma unroll
  for (int ww = 1; ww < 8; ++ww){
    sa += red[ww];
    sb += red[8 + ww];
  }
  float ia = 1.f / fmaxf(sa, 1e-6f);
  float ib = 1.f / fmaxf(sb, 1e-6f);
  out[(size_t)(b*NN + ip)*NN + tid]     = va * ia;
  out[(size_t)(b*NN + ip + 1)*NN + tid] = vb * ib;
}

extern "C" void kernel_launch(void* const* d_in, const int* in_sizes, int n_in,
                              void* d_out, int out_size, void* d_ws, size_t ws_size,
                              hipStream_t stream){
  const float* x      = (const float*)d_in[0];
  const float* mask   = (const float*)d_in[1];
  const float* sctx   = (const float*)d_in[2];
  const float* coords = (const float*)d_in[3];
  const float* W1     = (const float*)d_in[4];
  const float* b1     = (const float*)d_in[5];
  const float* W2     = (const float*)d_in[6];
  const float* b2     = (const float*)d_in[7];
  const float* We1    = (const float*)d_in[8];
  const float* be1    = (const float*)d_in[9];
  const float* We2    = (const float*)d_in[10];
  const float* be2    = (const float*)d_in[11];
  const float* sl     = (const float*)d_in[12];
  const float* ps     = (const float*)d_in[13];
  const float* ss     = (const float*)d_in[14];
  const float* tp     = (const float*)d_in[15];

  float*    ws     = (float*)d_ws;
  float*    hgp    = ws + OFF_H;
  float*    pvecp  = ws + OFF_PVEC;
  unsigned* hf16p  = (unsigned*)(ws + OFF_HF16);
  float*    invnp  = ws + OFF_INVN;
  short*    wa16p  = (short*)(ws + OFF_WA16);
  float*    wjfp   = ws + OFF_WJF;
  float*    wpfp   = ws + OFF_WPF;
  float*    unsym  = ws + OFF_UNSYM;
  float*    unsymT = ws + OFF_UNSYMT;
  float*    out    = (float*)d_out;

  k_front <<<304, 256, 0, stream>>>(x, mask, sctx, W1, b1, W2, b2, We1, be1,
                                    hgp, pvecp, hf16p, invnp, wa16p, wjfp, wpfp);
  k_logits<<<NB*NN/2, 512, 0, stream>>>(hgp, pvecp, hf16p, invnp, wa16p, wjfp,
                                        wpfp, coords, We2, be2, sl, ps, ss, tp,
                                        unsym, unsymT);
  k_sym   <<<NB*NN/2, 512, 0, stream>>>(unsym, unsymT, out);
}